// Round 18
// baseline (67.613 us; speedup 1.0000x reference)
//
#include <hip/hip_runtime.h>

typedef __bf16 bf16x8 __attribute__((ext_vector_type(8)));
typedef __bf16 bf16x4 __attribute__((ext_vector_type(4)));
typedef float  f32x4  __attribute__((ext_vector_type(4)));
typedef float  f32x16 __attribute__((ext_vector_type(16)));

#define GLD_LDS16(gsrc, ldst) \
  __builtin_amdgcn_global_load_lds((const __attribute__((address_space(1))) void*)(gsrc), \
                                   (__attribute__((address_space(3))) void*)(ldst), 16, 0, 0)

__device__ inline unsigned cvt_pk_bf16(float lo, float hi) {
  unsigned r;
  asm("v_cvt_pk_bf16_f32 %0, %1, %2" : "=v"(r) : "v"(lo), "v"(hi));
  return r;
}
__device__ inline void pl32_swap(unsigned& a, unsigned& b) {
  // NOTE: a and b MUST be distinct values; two copies of one value can be
  // register-coalesced -> in-place half-swap -> silent corruption (round-16 bug).
  asm volatile("v_permlane32_swap_b32 %0, %1" : "+v"(a), "+v"(b));
}
__device__ inline f32x16 zero16() {
  f32x16 z;
#pragma unroll
  for (int i = 0; i < 16; ++i) z[i] = 0.f;
  return z;
}

// ---------------- 1) GroupNorm partial sums (+ one-time w_qkv hi/lo split) ----------------
__global__ __launch_bounds__(256) void gn_partial_k(const float* __restrict__ x,
                                                    const float* __restrict__ w_qkv,
                                                    float* __restrict__ partial,
                                                    __bf16* __restrict__ whi,
                                                    __bf16* __restrict__ wlo) {
  __shared__ float red[2][4];
  const int t = threadIdx.x;
  if (blockIdx.x < 48) {   // split w_qkv (192x64) into bf16 hi/lo once
    const int idx = blockIdx.x * 256 + t;
    float wv = w_qkv[idx];
    __bf16 hh = (__bf16)wv;
    whi[idx] = hh;
    wlo[idx] = (__bf16)(wv - (float)hh);
  }
  const float4* base = (const float4*)(x + (size_t)blockIdx.x * 4096);
  float s = 0.f, sq = 0.f;
#pragma unroll
  for (int kk = 0; kk < 4; ++kk) {
    float4 v = base[t + kk * 256];
    s  += (v.x + v.y) + (v.z + v.w);
    sq += (v.x * v.x + v.y * v.y) + (v.z * v.z + v.w * v.w);
  }
#pragma unroll
  for (int o = 32; o >= 1; o >>= 1) {
    s  += __shfl_down(s, o, 64);
    sq += __shfl_down(sq, o, 64);
  }
  if ((t & 63) == 0) { red[0][t >> 6] = s; red[1][t >> 6] = sq; }
  __syncthreads();
  if (t == 0) {
    float S  = (red[0][0] + red[0][1]) + (red[0][2] + red[0][3]);
    float SQ = (red[1][0] + red[1][1]) + (red[1][2] + red[1][3]);
    partial[blockIdx.x * 2]     = S;
    partial[blockIdx.x * 2 + 1] = SQ;
  }
}

// ---------------- 2) QKV split-precision MFMA GEMM, gn_final fused in-block ----------------
__global__ __launch_bounds__(256) void qkv_k(const float* __restrict__ x,
                                             const float* __restrict__ partial,
                                             const float* __restrict__ gamma,
                                             const float* __restrict__ beta,
                                             const __bf16* __restrict__ whi,
                                             const __bf16* __restrict__ wlo,
                                             const float* __restrict__ b_qkv,
                                             __bf16* __restrict__ qo,
                                             __bf16* __restrict__ ko,
                                             __bf16* __restrict__ vto) {
  __shared__ float mu_s[8], rs_s[8], sc_l[128];
  const int tid  = threadIdx.x;
  const int lane = tid & 63, w = tid >> 6;
  const int px16 = lane & 15, grp = lane >> 4;
  const int b    = blockIdx.x >> 6;
  const int s0   = (blockIdx.x & 63) * 64;
  const int pxg  = s0 + w * 16 + px16;

  if (tid < 8) {
    float S = 0.f, SQ = 0.f;
#pragma unroll
    for (int i = 0; i < 8; ++i) {
      S  += partial[((b * 8 + tid) * 8 + i) * 2];
      SQ += partial[((b * 8 + tid) * 8 + i) * 2 + 1];
    }
    float mean = S * (1.f / 32768.f);
    float var  = SQ * (1.f / 32768.f) - mean * mean;
    mu_s[tid] = mean;
    rs_s[tid] = rsqrtf(fmaxf(var, 0.f) + 1e-5f);
  }
  __syncthreads();
  if (tid < 64) {
    const int g = tid >> 3;
    float scale = rs_s[g] * gamma[tid];
    sc_l[tid * 2]     = scale;
    sc_l[tid * 2 + 1] = beta[tid] - mu_s[g] * scale;
  }
  __syncthreads();

  bf16x8 bh[2], bl[2];
#pragma unroll
  for (int kk = 0; kk < 2; ++kk) {
    bf16x8 hv, lv;
#pragma unroll
    for (int i = 0; i < 8; ++i) {
      const int c = kk * 32 + grp * 8 + i;
      float xv = x[((size_t)(b * 64 + c) * 4096) + pxg];
      float xn = fmaf(xv, sc_l[c * 2], sc_l[c * 2 + 1]);
      __bf16 hh = (__bf16)xn;
      hv[i] = hh;
      lv[i] = (__bf16)(xn - (float)hh);
    }
    bh[kk] = hv;
    bl[kk] = lv;
  }

  f32x4 acc[12];
#pragma unroll
  for (int ot = 0; ot < 12; ++ot) {
    const int o = ot * 16 + px16;
    f32x4 a = {0.f, 0.f, 0.f, 0.f};
#pragma unroll
    for (int kk = 0; kk < 2; ++kk) {
      const size_t wo = (size_t)o * 64 + kk * 32 + grp * 8;
      bf16x8 ah = *(const bf16x8*)(whi + wo);
      bf16x8 al = *(const bf16x8*)(wlo + wo);
      a = __builtin_amdgcn_mfma_f32_16x16x32_bf16(ah, bh[kk], a, 0, 0, 0);
      a = __builtin_amdgcn_mfma_f32_16x16x32_bf16(ah, bl[kk], a, 0, 0, 0);
      a = __builtin_amdgcn_mfma_f32_16x16x32_bf16(al, bh[kk], a, 0, 0, 0);
    }
    acc[ot] = a;
  }

#pragma unroll
  for (int ot = 0; ot < 4; ++ot) {   // Q, pre-scaled 0.125*log2(e)
    const int ob = ot * 16 + grp * 4;
    float4 bias = *(const float4*)(b_qkv + ob);
    f32x4 a = acc[ot];
    bf16x4 qv = {(__bf16)((a[0] + bias.x) * 0.18033688f),
                 (__bf16)((a[1] + bias.y) * 0.18033688f),
                 (__bf16)((a[2] + bias.z) * 0.18033688f),
                 (__bf16)((a[3] + bias.w) * 0.18033688f)};
    *(bf16x4*)(qo + ((size_t)b * 4096 + pxg) * 64 + ob) = qv;
  }
#pragma unroll
  for (int ot = 4; ot < 8; ++ot) {   // K
    const int ob = (ot - 4) * 16 + grp * 4;
    float4 bias = *(const float4*)(b_qkv + 64 + ob);
    f32x4 a = acc[ot];
    bf16x4 kv = {(__bf16)(a[0] + bias.x), (__bf16)(a[1] + bias.y),
                 (__bf16)(a[2] + bias.z), (__bf16)(a[3] + bias.w)};
    *(bf16x4*)(ko + ((size_t)b * 4096 + pxg) * 64 + ob) = kv;
  }
#pragma unroll
  for (int ot = 8; ot < 12; ++ot) {  // V^T
    const int ob = (ot - 8) * 16 + grp * 4;
    float4 bias = *(const float4*)(b_qkv + 128 + ob);
    f32x4 a = acc[ot];
#pragma unroll
    for (int r = 0; r < 4; ++r) {
      float bv = (r == 0) ? bias.x : (r == 1) ? bias.y : (r == 2) ? bias.z : bias.w;
      vto[((size_t)(b * 64 + ob + r)) * 4096 + pxg] = (__bf16)(a[r] + bv);
    }
  }
}

// ---------------- 3) flash attention: 3 barriers total, free-run spans of 4 tiles ----------------
// 512 blocks x 512 threads (8 waves), 2 blocks/CU (64KB LDS, 128 VGPR). 4 K + 4 V buffers
// hold tiles t0..t3 SIMULTANEOUSLY -> after one vmcnt(0)+barrier, waves compute 4 tiles with
// zero intervening syncs (no reuse hazard; compiler inserts lgkmcnt per-use). Then
// barrier (retire) -> stage t4..t7 -> vmcnt(0)+barrier -> free-run 4 more. The exposed
// staging of the 2nd half is hidden by the sibling block on the same CU (desynced phases).
__global__ __launch_bounds__(512, 2) void attn_k(const __bf16* __restrict__ q,
                                                 const __bf16* __restrict__ k,
                                                 const __bf16* __restrict__ vt,
                                                 __bf16* __restrict__ opart,
                                                 float* __restrict__ mlpart) {
  __shared__ __bf16 k_lds[4][4096];   // 64 keys x 64 d each, swizzled slots (8KB)
  __shared__ __bf16 v_lds[4][4096];   // 64 d x 64 keys each, swizzled slots

  const int tid  = threadIdx.x;
  const int lane = tid & 63, w = tid >> 6;
  const int col  = lane & 31;
  const int h    = lane >> 5;
  const int swz  = col & 7;

  const int blk  = blockIdx.x;
  const int xcd  = blk & 7;
  const int b    = xcd >> 1;
  const int rest = blk >> 3;
  const int seg  = rest >> 3;
  const int qblk = (rest & 7) | ((xcd & 1) << 3);
  const int q0   = qblk * 256 + w * 32;
  const int j0b  = seg * 512;

  const __bf16* qp = q  + (size_t)b * 4096 * 64;
  const __bf16* kp = k  + (size_t)b * 4096 * 64;
  const __bf16* vp = vt + (size_t)b * 64 * 4096;

  bf16x8 qf[4];
#pragma unroll
  for (int kk = 0; kk < 4; ++kk)
    qf[kk] = *(const bf16x8*)(qp + (size_t)(q0 + col) * 64 + kk * 16 + h * 8);

  f32x16 acc0 = zero16(), acc1 = zero16();
  float m = -1e30f, l = 0.f;

  const int soff = tid * 16;
  const int sj = soff >> 7;
  const int sc2 = ((soff >> 4) & 7) ^ (sj & 7);

  auto stage = [&](int buf, int j0) {
    GLD_LDS16(kp + (size_t)(j0 + sj) * 64 + sc2 * 8, (char*)(&k_lds[buf][0]) + soff);
    GLD_LDS16(vp + (size_t)sj * 4096 + j0 + sc2 * 8, (char*)(&v_lds[buf][0]) + soff);
  };

  auto compute = [&](int buf) {
    const char* kbase = (const char*)&k_lds[buf][0];
    const char* vbase = (const char*)&v_lds[buf][0];

    // ---- S^T = K · Q^T (exp2 domain) ----
    f32x16 sa0 = zero16(), sa1 = zero16();
#pragma unroll
    for (int kk = 0; kk < 4; ++kk) {
      bf16x8 kf0 = *(const bf16x8*)(kbase + col * 128        + (((2 * kk + h) ^ swz) << 4));
      bf16x8 kf1 = *(const bf16x8*)(kbase + (32 + col) * 128 + (((2 * kk + h) ^ swz) << 4));
      sa0 = __builtin_amdgcn_mfma_f32_32x32x16_bf16(kf0, qf[kk], sa0, 0, 0, 0);
      sa1 = __builtin_amdgcn_mfma_f32_32x32x16_bf16(kf1, qf[kk], sa1, 0, 0, 0);
    }

    // ---- online softmax, defer-rescale (T13, THR=8 in log2 units) ----
    float x0 = fmaxf(fmaxf(sa0[0], sa0[1]),   fmaxf(sa0[2], sa0[3]));
    float x1 = fmaxf(fmaxf(sa0[4], sa0[5]),   fmaxf(sa0[6], sa0[7]));
    float x2 = fmaxf(fmaxf(sa0[8], sa0[9]),   fmaxf(sa0[10], sa0[11]));
    float x3 = fmaxf(fmaxf(sa0[12], sa0[13]), fmaxf(sa0[14], sa0[15]));
    float y0 = fmaxf(fmaxf(sa1[0], sa1[1]),   fmaxf(sa1[2], sa1[3]));
    float y1 = fmaxf(fmaxf(sa1[4], sa1[5]),   fmaxf(sa1[6], sa1[7]));
    float y2 = fmaxf(fmaxf(sa1[8], sa1[9]),   fmaxf(sa1[10], sa1[11]));
    float y3 = fmaxf(fmaxf(sa1[12], sa1[13]), fmaxf(sa1[14], sa1[15]));
    float mx = fmaxf(fmaxf(fmaxf(x0, x1), fmaxf(x2, x3)),
                     fmaxf(fmaxf(y0, y1), fmaxf(y2, y3)));
    mx = fmaxf(mx, __shfl_xor(mx, 32, 64));
    if (!__all(mx <= m + 8.f)) {     // rescale only when the running max really grew
      float mn = fmaxf(m, mx);
      float sf = exp2f(m - mn);
      m = mn;
      l *= sf;
      acc0 *= sf;
      acc1 *= sf;
    }
#pragma unroll
    for (int r = 0; r < 16; ++r) sa0[r] = exp2f(sa0[r] - m);
#pragma unroll
    for (int r = 0; r < 16; ++r) sa1[r] = exp2f(sa1[r] - m);
    // pairwise tree-sum (5-level dep chain)
    float s00 = (sa0[0] + sa0[1]) + (sa0[2] + sa0[3]);
    float s01 = (sa0[4] + sa0[5]) + (sa0[6] + sa0[7]);
    float s02 = (sa0[8] + sa0[9]) + (sa0[10] + sa0[11]);
    float s03 = (sa0[12] + sa0[13]) + (sa0[14] + sa0[15]);
    float s10 = (sa1[0] + sa1[1]) + (sa1[2] + sa1[3]);
    float s11 = (sa1[4] + sa1[5]) + (sa1[6] + sa1[7]);
    float s12 = (sa1[8] + sa1[9]) + (sa1[10] + sa1[11]);
    float s13 = (sa1[12] + sa1[13]) + (sa1[14] + sa1[15]);
    l += ((s00 + s01) + (s02 + s03)) + ((s10 + s11) + (s12 + s13));

    // ---- pack P to bf16 + permlane32_swap -> B-fragments in registers ----
    unsigned w0[8], w1[8];
#pragma unroll
    for (int qd = 0; qd < 4; ++qd) {
      w0[qd * 2]     = cvt_pk_bf16(sa0[4 * qd],     sa0[4 * qd + 1]);
      w0[qd * 2 + 1] = cvt_pk_bf16(sa0[4 * qd + 2], sa0[4 * qd + 3]);
      w1[qd * 2]     = cvt_pk_bf16(sa1[4 * qd],     sa1[4 * qd + 1]);
      w1[qd * 2 + 1] = cvt_pk_bf16(sa1[4 * qd + 2], sa1[4 * qd + 3]);
    }
    bf16x8 pa[4];
#pragma unroll
    for (int c = 0; c < 4; ++c) {
      const unsigned* wt = (c < 2) ? w0 : w1;
      unsigned a0 = wt[(2 * (c & 1)) * 2],     b0 = wt[(2 * (c & 1) + 1) * 2];
      unsigned a1 = wt[(2 * (c & 1)) * 2 + 1], b1 = wt[(2 * (c & 1) + 1) * 2 + 1];
      pl32_swap(a0, b0);
      pl32_swap(a1, b1);
      uint4 u; u.x = a0; u.y = a1; u.z = b0; u.w = b1;
      pa[c] = __builtin_bit_cast(bf16x8, u);
    }

    // ---- O^T += V^T · P^T ----
#pragma unroll
    for (int c = 0; c < 4; ++c) {
      bf16x8 vf0 = *(const bf16x8*)(vbase + col * 128        + (((2 * c + h) ^ swz) << 4));
      bf16x8 vf1 = *(const bf16x8*)(vbase + (32 + col) * 128 + (((2 * c + h) ^ swz) << 4));
      acc0 = __builtin_amdgcn_mfma_f32_32x32x16_bf16(vf0, pa[c], acc0, 0, 0, 0);
      acc1 = __builtin_amdgcn_mfma_f32_32x32x16_bf16(vf1, pa[c], acc1, 0, 0, 0);
    }
  };

  // ---- first half: tiles t0..t3 resident in the 4 buffers ----
  stage(0, j0b);
  stage(1, j0b + 64);
  stage(2, j0b + 128);
  stage(3, j0b + 192);
  asm volatile("s_waitcnt vmcnt(0)" ::: "memory");
  __builtin_amdgcn_s_barrier();        // A: everything resident (incl. qf)
#pragma unroll
  for (int t = 0; t < 4; ++t) compute(t);   // free-run, no syncs

  __builtin_amdgcn_s_barrier();        // B: all waves done reading t0..t3
  stage(0, j0b + 256);
  stage(1, j0b + 320);
  stage(2, j0b + 384);
  stage(3, j0b + 448);
  asm volatile("s_waitcnt vmcnt(0)" ::: "memory");
  __builtin_amdgcn_s_barrier();        // C: t4..t7 resident
#pragma unroll
  for (int t = 0; t < 4; ++t) compute(t);   // free-run

  // ---- epilogue: un-normalized O^T (bf16, qrow-major layout) + (m, l) ----
  float lf = l + __shfl_xor(l, 32, 64);
  const int qrow = q0 + col;
  __bf16* ob = opart + (((size_t)(b * 4096 + qrow)) * 8 + seg) * 64;
#pragma unroll
  for (int rq = 0; rq < 4; ++rq) {
    const int d0 = 8 * rq + 4 * h;
    bf16x4 o0 = {(__bf16)acc0[4 * rq], (__bf16)acc0[4 * rq + 1],
                 (__bf16)acc0[4 * rq + 2], (__bf16)acc0[4 * rq + 3]};
    bf16x4 o1 = {(__bf16)acc1[4 * rq], (__bf16)acc1[4 * rq + 1],
                 (__bf16)acc1[4 * rq + 2], (__bf16)acc1[4 * rq + 3]};
    *(bf16x4*)(ob + d0)      = o0;
    *(bf16x4*)(ob + 32 + d0) = o1;
  }
  if (h == 0) {
    float2 mlv; mlv.x = m; mlv.y = lf;   // m in log2 domain
    *(float2*)(mlpart + ((size_t)(b * 8 + seg) * 4096 + qrow) * 2) = mlv;
  }
}

// ---------------- 4) split-K combine (qrow-major opart) + proj + residual ----------------
__global__ __launch_bounds__(256) void proj_k(const __bf16* __restrict__ opart,
                                              const float* __restrict__ mlpart,
                                              const float* __restrict__ x,
                                              const float* __restrict__ w_proj,
                                              const float* __restrict__ b_proj,
                                              float* __restrict__ out) {
  __shared__ float wseg[8][32];
  __shared__ float a_lds[32 * 68];
  __shared__ float o_lds[64 * 33];
  const int t  = threadIdx.x;
  const int b  = blockIdx.x >> 7;
  const int s0 = (blockIdx.x & 127) * 32;

  if (t < 32) {
    const int rowg = s0 + t;
    float ms[8], ls[8], es[8];
    float M = -1e30f;
#pragma unroll
    for (int s = 0; s < 8; ++s) {
      float2 ml = *(const float2*)(mlpart + ((size_t)(b * 8 + s) * 4096 + rowg) * 2);
      ms[s] = ml.x; ls[s] = ml.y;
      M = fmaxf(M, ms[s]);
    }
    float L = 0.f;
#pragma unroll
    for (int s = 0; s < 8; ++s) { es[s] = exp2f(ms[s] - M); L += es[s] * ls[s]; }
    float invL = 1.f / L;
#pragma unroll
    for (int s = 0; s < 8; ++s) wseg[s][t] = es[s] * invL;
  }
  __syncthreads();

  for (int i = t; i < 512; i += 256) {
    const int px = i >> 4, c4 = i & 15;
    // qrow-major opart: all 8 segs for this px are contiguous (8 x 64 ch = 1KB)
    const __bf16* obase = opart + (((size_t)(b * 4096 + s0 + px)) * 8) * 64 + c4 * 4;
    float4 a = {0.f, 0.f, 0.f, 0.f};
#pragma unroll
    for (int s = 0; s < 8; ++s) {
      bf16x4 v = *(const bf16x4*)(obase + s * 64);
      float wv = wseg[s][px];
      a.x += wv * (float)v[0]; a.y += wv * (float)v[1];
      a.z += wv * (float)v[2]; a.w += wv * (float)v[3];
    }
    *(float4*)(&a_lds[px * 68 + c4 * 4]) = a;
  }

  const int o = t & 63, wg = t >> 6;
  float4 wr[16];
  const float4* wrow = (const float4*)(w_proj + o * 64);
#pragma unroll
  for (int i = 0; i < 16; ++i) wr[i] = wrow[i];
  const float bias = b_proj[o];
  __syncthreads();

  for (int pp = 0; pp < 8; ++pp) {
    const int px = wg * 8 + pp;
    const float4* ar = (const float4*)&a_lds[px * 68];
    float a0 = bias, a1 = 0.f, a2 = 0.f, a3 = 0.f;
#pragma unroll
    for (int i = 0; i < 16; i += 4) {
      float4 x0 = ar[i], x1 = ar[i + 1], x2 = ar[i + 2], x3 = ar[i + 3];
      a0 += wr[i    ].x * x0.x + wr[i    ].y * x0.y + wr[i    ].z * x0.z + wr[i    ].w * x0.w;
      a1 += wr[i + 1].x * x1.x + wr[i + 1].y * x1.y + wr[i + 1].z * x1.z + wr[i + 1].w * x1.w;
      a2 += wr[i + 2].x * x2.x + wr[i + 2].y * x2.y + wr[i + 2].z * x2.z + wr[i + 2].w * x2.w;
      a3 += wr[i + 3].x * x3.x + wr[i + 3].y * x3.y + wr[i + 3].z * x3.z + wr[i + 3].w * x3.w;
    }
    o_lds[o * 33 + px] = (a0 + a1) + (a2 + a3);
  }
  __syncthreads();
  for (int idx = t; idx < 2048; idx += 256) {
    const int c = idx >> 5, px = idx & 31;
    const size_t gi = ((size_t)(b * 64 + c)) * 4096 + s0 + px;
    out[gi] = o_lds[c * 33 + px] + x[gi];
  }
}

// ---------------- launch ----------------
extern "C" void kernel_launch(void* const* d_in, const int* in_sizes, int n_in,
                              void* d_out, int out_size, void* d_ws, size_t ws_size,
                              hipStream_t stream) {
  const float* x      = (const float*)d_in[0];
  const float* gamma  = (const float*)d_in[1];
  const float* beta   = (const float*)d_in[2];
  const float* w_qkv  = (const float*)d_in[3];
  const float* b_qkv  = (const float*)d_in[4];
  const float* w_proj = (const float*)d_in[5];
  const float* b_proj = (const float*)d_in[6];
  float* out = (float*)d_out;

  char* ws = (char*)d_ws;
  float*  partial = (float*)ws;                          // 512 f32  @ 0
  __bf16* whi     = (__bf16*)(ws + 4096);                // 24KB
  __bf16* wlo     = whi + 12288;                         // 24KB
  __bf16* qb  = (__bf16*)(ws + 65536);                   // 2MB
  __bf16* kb  = qb  + (size_t)4 * 4096 * 64;             // 2MB
  __bf16* vtb = kb  + (size_t)4 * 4096 * 64;             // 2MB
  __bf16* opart = vtb + (size_t)4 * 4096 * 64;           // 16MB (bf16), qrow-major
  float*  mlpart = (float*)(opart + (size_t)4 * 8 * 4096 * 64);  // 1MB

  gn_partial_k<<<256, 256, 0, stream>>>(x, w_qkv, partial, whi, wlo);
  qkv_k<<<256, 256, 0, stream>>>(x, partial, gamma, beta, whi, wlo, b_qkv, qb, kb, vtb);
  attn_k<<<512, 512, 0, stream>>>(qb, kb, vtb, opart, mlpart);
  proj_k<<<512, 256, 0, stream>>>(opart, mlpart, x, w_proj, b_proj, out);
}

// Round 19
// 66.423 us; speedup vs baseline: 1.0179x; 1.0179x over previous
//
#include <hip/hip_runtime.h>

typedef __bf16 bf16x8 __attribute__((ext_vector_type(8)));
typedef __bf16 bf16x4 __attribute__((ext_vector_type(4)));
typedef float  f32x4  __attribute__((ext_vector_type(4)));
typedef float  f32x16 __attribute__((ext_vector_type(16)));

#define GLD_LDS16(gsrc, ldst) \
  __builtin_amdgcn_global_load_lds((const __attribute__((address_space(1))) void*)(gsrc), \
                                   (__attribute__((address_space(3))) void*)(ldst), 16, 0, 0)

__device__ inline unsigned cvt_pk_bf16(float lo, float hi) {
  unsigned r;
  asm("v_cvt_pk_bf16_f32 %0, %1, %2" : "=v"(r) : "v"(lo), "v"(hi));
  return r;
}
__device__ inline void pl32_swap(unsigned& a, unsigned& b) {
  // NOTE: a and b MUST be distinct values; two copies of one value can be
  // register-coalesced -> in-place half-swap -> silent corruption (round-16 bug).
  asm volatile("v_permlane32_swap_b32 %0, %1" : "+v"(a), "+v"(b));
}
__device__ inline f32x16 zero16() {
  f32x16 z;
#pragma unroll
  for (int i = 0; i < 16; ++i) z[i] = 0.f;
  return z;
}

// ---------------- 1) GroupNorm partial sums (+ one-time w_qkv hi/lo split) ----------------
__global__ __launch_bounds__(256) void gn_partial_k(const float* __restrict__ x,
                                                    const float* __restrict__ w_qkv,
                                                    float* __restrict__ partial,
                                                    __bf16* __restrict__ whi,
                                                    __bf16* __restrict__ wlo) {
  __shared__ float red[2][4];
  const int t = threadIdx.x;
  if (blockIdx.x < 48) {   // split w_qkv (192x64) into bf16 hi/lo once
    const int idx = blockIdx.x * 256 + t;
    float wv = w_qkv[idx];
    __bf16 hh = (__bf16)wv;
    whi[idx] = hh;
    wlo[idx] = (__bf16)(wv - (float)hh);
  }
  const float4* base = (const float4*)(x + (size_t)blockIdx.x * 4096);
  float s = 0.f, sq = 0.f;
#pragma unroll
  for (int kk = 0; kk < 4; ++kk) {
    float4 v = base[t + kk * 256];
    s  += (v.x + v.y) + (v.z + v.w);
    sq += (v.x * v.x + v.y * v.y) + (v.z * v.z + v.w * v.w);
  }
#pragma unroll
  for (int o = 32; o >= 1; o >>= 1) {
    s  += __shfl_down(s, o, 64);
    sq += __shfl_down(sq, o, 64);
  }
  if ((t & 63) == 0) { red[0][t >> 6] = s; red[1][t >> 6] = sq; }
  __syncthreads();
  if (t == 0) {
    float S  = (red[0][0] + red[0][1]) + (red[0][2] + red[0][3]);
    float SQ = (red[1][0] + red[1][1]) + (red[1][2] + red[1][3]);
    partial[blockIdx.x * 2]     = S;
    partial[blockIdx.x * 2 + 1] = SQ;
  }
}

// ---------------- 2) QKV split-precision MFMA GEMM, gn_final fused in-block ----------------
__global__ __launch_bounds__(256) void qkv_k(const float* __restrict__ x,
                                             const float* __restrict__ partial,
                                             const float* __restrict__ gamma,
                                             const float* __restrict__ beta,
                                             const __bf16* __restrict__ whi,
                                             const __bf16* __restrict__ wlo,
                                             const float* __restrict__ b_qkv,
                                             __bf16* __restrict__ qo,
                                             __bf16* __restrict__ ko,
                                             __bf16* __restrict__ vto) {
  __shared__ float mu_s[8], rs_s[8], sc_l[128];
  const int tid  = threadIdx.x;
  const int lane = tid & 63, w = tid >> 6;
  const int px16 = lane & 15, grp = lane >> 4;
  const int b    = blockIdx.x >> 6;
  const int s0   = (blockIdx.x & 63) * 64;
  const int pxg  = s0 + w * 16 + px16;

  if (tid < 8) {
    float S = 0.f, SQ = 0.f;
#pragma unroll
    for (int i = 0; i < 8; ++i) {
      S  += partial[((b * 8 + tid) * 8 + i) * 2];
      SQ += partial[((b * 8 + tid) * 8 + i) * 2 + 1];
    }
    float mean = S * (1.f / 32768.f);
    float var  = SQ * (1.f / 32768.f) - mean * mean;
    mu_s[tid] = mean;
    rs_s[tid] = rsqrtf(fmaxf(var, 0.f) + 1e-5f);
  }
  __syncthreads();
  if (tid < 64) {
    const int g = tid >> 3;
    float scale = rs_s[g] * gamma[tid];
    sc_l[tid * 2]     = scale;
    sc_l[tid * 2 + 1] = beta[tid] - mu_s[g] * scale;
  }
  __syncthreads();

  bf16x8 bh[2], bl[2];
#pragma unroll
  for (int kk = 0; kk < 2; ++kk) {
    bf16x8 hv, lv;
#pragma unroll
    for (int i = 0; i < 8; ++i) {
      const int c = kk * 32 + grp * 8 + i;
      float xv = x[((size_t)(b * 64 + c) * 4096) + pxg];
      float xn = fmaf(xv, sc_l[c * 2], sc_l[c * 2 + 1]);
      __bf16 hh = (__bf16)xn;
      hv[i] = hh;
      lv[i] = (__bf16)(xn - (float)hh);
    }
    bh[kk] = hv;
    bl[kk] = lv;
  }

  f32x4 acc[12];
#pragma unroll
  for (int ot = 0; ot < 12; ++ot) {
    const int o = ot * 16 + px16;
    f32x4 a = {0.f, 0.f, 0.f, 0.f};
#pragma unroll
    for (int kk = 0; kk < 2; ++kk) {
      const size_t wo = (size_t)o * 64 + kk * 32 + grp * 8;
      bf16x8 ah = *(const bf16x8*)(whi + wo);
      bf16x8 al = *(const bf16x8*)(wlo + wo);
      a = __builtin_amdgcn_mfma_f32_16x16x32_bf16(ah, bh[kk], a, 0, 0, 0);
      a = __builtin_amdgcn_mfma_f32_16x16x32_bf16(ah, bl[kk], a, 0, 0, 0);
      a = __builtin_amdgcn_mfma_f32_16x16x32_bf16(al, bh[kk], a, 0, 0, 0);
    }
    acc[ot] = a;
  }

#pragma unroll
  for (int ot = 0; ot < 4; ++ot) {   // Q, pre-scaled 0.125*log2(e)
    const int ob = ot * 16 + grp * 4;
    float4 bias = *(const float4*)(b_qkv + ob);
    f32x4 a = acc[ot];
    bf16x4 qv = {(__bf16)((a[0] + bias.x) * 0.18033688f),
                 (__bf16)((a[1] + bias.y) * 0.18033688f),
                 (__bf16)((a[2] + bias.z) * 0.18033688f),
                 (__bf16)((a[3] + bias.w) * 0.18033688f)};
    *(bf16x4*)(qo + ((size_t)b * 4096 + pxg) * 64 + ob) = qv;
  }
#pragma unroll
  for (int ot = 4; ot < 8; ++ot) {   // K
    const int ob = (ot - 4) * 16 + grp * 4;
    float4 bias = *(const float4*)(b_qkv + 64 + ob);
    f32x4 a = acc[ot];
    bf16x4 kv = {(__bf16)(a[0] + bias.x), (__bf16)(a[1] + bias.y),
                 (__bf16)(a[2] + bias.z), (__bf16)(a[3] + bias.w)};
    *(bf16x4*)(ko + ((size_t)b * 4096 + pxg) * 64 + ob) = kv;
  }
#pragma unroll
  for (int ot = 8; ot < 12; ++ot) {  // V^T
    const int ob = (ot - 8) * 16 + grp * 4;
    float4 bias = *(const float4*)(b_qkv + 128 + ob);
    f32x4 a = acc[ot];
#pragma unroll
    for (int r = 0; r < 4; ++r) {
      float bv = (r == 0) ? bias.x : (r == 1) ? bias.y : (r == 2) ? bias.z : bias.w;
      vto[((size_t)(b * 64 + ob + r)) * 4096 + pxg] = (__bf16)(a[r] + bv);
    }
  }
}

// ---------------- 3) flash attention: 4-buffer, 2 tiles/barrier; no setprio; shfl cross-lane ----------------
// Round-17 verified best. 512 blocks x 512 threads (8 waves), 2 blocks/CU (64KB LDS, 128 VGPR).
// Tiles t0..t7 -> buf t%4; one barrier per 2 tiles; counted vmcnt keeps later tiles in flight.
__global__ __launch_bounds__(512, 2) void attn_k(const __bf16* __restrict__ q,
                                                 const __bf16* __restrict__ k,
                                                 const __bf16* __restrict__ vt,
                                                 __bf16* __restrict__ opart,
                                                 float* __restrict__ mlpart) {
  __shared__ __bf16 k_lds[4][4096];   // 64 keys x 64 d each, swizzled slots (8KB)
  __shared__ __bf16 v_lds[4][4096];   // 64 d x 64 keys each, swizzled slots

  const int tid  = threadIdx.x;
  const int lane = tid & 63, w = tid >> 6;
  const int col  = lane & 31;
  const int h    = lane >> 5;
  const int swz  = col & 7;

  const int blk  = blockIdx.x;
  const int xcd  = blk & 7;
  const int b    = xcd >> 1;
  const int rest = blk >> 3;
  const int seg  = rest >> 3;
  const int qblk = (rest & 7) | ((xcd & 1) << 3);
  const int q0   = qblk * 256 + w * 32;
  const int j0b  = seg * 512;

  const __bf16* qp = q  + (size_t)b * 4096 * 64;
  const __bf16* kp = k  + (size_t)b * 4096 * 64;
  const __bf16* vp = vt + (size_t)b * 64 * 4096;

  bf16x8 qf[4];
#pragma unroll
  for (int kk = 0; kk < 4; ++kk)
    qf[kk] = *(const bf16x8*)(qp + (size_t)(q0 + col) * 64 + kk * 16 + h * 8);
  __builtin_amdgcn_sched_barrier(0);   // pin qf loads before staging (vmcnt ledger)

  f32x16 acc0 = zero16(), acc1 = zero16();
  float m = -1e30f, l = 0.f;

  const int soff = tid * 16;
  const int sj = soff >> 7;
  const int sc2 = ((soff >> 4) & 7) ^ (sj & 7);

  auto stage = [&](int buf, int j0) {
    GLD_LDS16(kp + (size_t)(j0 + sj) * 64 + sc2 * 8, (char*)(&k_lds[buf][0]) + soff);
    GLD_LDS16(vp + (size_t)sj * 4096 + j0 + sc2 * 8, (char*)(&v_lds[buf][0]) + soff);
  };

  stage(0, j0b);
  stage(1, j0b + 64);
  stage(2, j0b + 128);
  stage(3, j0b + 192);

#pragma unroll
  for (int kt = 0; kt < 4; ++kt) {
    // wait for this iteration's TWO tiles (2kt, 2kt+1)
    if (kt == 0) asm volatile("s_waitcnt vmcnt(4)" ::: "memory");
    else         asm volatile("s_waitcnt vmcnt(0)" ::: "memory");
    __builtin_amdgcn_s_barrier();      // loads landed + previous iter's buffers retired

    if (kt == 1) { stage(0, j0b + 256); stage(1, j0b + 320); }  // t4,t5 -> b0,b1
    if (kt == 2) { stage(2, j0b + 384); stage(3, j0b + 448); }  // t6,t7 -> b2,b3

#pragma unroll
    for (int sub = 0; sub < 2; ++sub) {
      const int buf = (2 * kt + sub) & 3;
      const char* kbase = (const char*)&k_lds[buf][0];
      const char* vbase = (const char*)&v_lds[buf][0];

      // ---- S^T = K · Q^T (exp2 domain) ----
      f32x16 sa0 = zero16(), sa1 = zero16();
#pragma unroll
      for (int kk = 0; kk < 4; ++kk) {
        bf16x8 kf0 = *(const bf16x8*)(kbase + col * 128        + (((2 * kk + h) ^ swz) << 4));
        bf16x8 kf1 = *(const bf16x8*)(kbase + (32 + col) * 128 + (((2 * kk + h) ^ swz) << 4));
        sa0 = __builtin_amdgcn_mfma_f32_32x32x16_bf16(kf0, qf[kk], sa0, 0, 0, 0);
        sa1 = __builtin_amdgcn_mfma_f32_32x32x16_bf16(kf1, qf[kk], sa1, 0, 0, 0);
      }

      // ---- online softmax, defer-rescale (T13, THR=8 in log2 units) ----
      float x0 = fmaxf(fmaxf(sa0[0], sa0[1]),   fmaxf(sa0[2], sa0[3]));
      float x1 = fmaxf(fmaxf(sa0[4], sa0[5]),   fmaxf(sa0[6], sa0[7]));
      float x2 = fmaxf(fmaxf(sa0[8], sa0[9]),   fmaxf(sa0[10], sa0[11]));
      float x3 = fmaxf(fmaxf(sa0[12], sa0[13]), fmaxf(sa0[14], sa0[15]));
      float y0 = fmaxf(fmaxf(sa1[0], sa1[1]),   fmaxf(sa1[2], sa1[3]));
      float y1 = fmaxf(fmaxf(sa1[4], sa1[5]),   fmaxf(sa1[6], sa1[7]));
      float y2 = fmaxf(fmaxf(sa1[8], sa1[9]),   fmaxf(sa1[10], sa1[11]));
      float y3 = fmaxf(fmaxf(sa1[12], sa1[13]), fmaxf(sa1[14], sa1[15]));
      float mx = fmaxf(fmaxf(fmaxf(x0, x1), fmaxf(x2, x3)),
                       fmaxf(fmaxf(y0, y1), fmaxf(y2, y3)));
      mx = fmaxf(mx, __shfl_xor(mx, 32, 64));
      if (!__all(mx <= m + 8.f)) {     // rescale only when the running max really grew
        float mn = fmaxf(m, mx);
        float sf = exp2f(m - mn);
        m = mn;
        l *= sf;
        acc0 *= sf;
        acc1 *= sf;
      }
#pragma unroll
      for (int r = 0; r < 16; ++r) sa0[r] = exp2f(sa0[r] - m);
#pragma unroll
      for (int r = 0; r < 16; ++r) sa1[r] = exp2f(sa1[r] - m);
      // pairwise tree-sum (5-level dep chain)
      float s00 = (sa0[0] + sa0[1]) + (sa0[2] + sa0[3]);
      float s01 = (sa0[4] + sa0[5]) + (sa0[6] + sa0[7]);
      float s02 = (sa0[8] + sa0[9]) + (sa0[10] + sa0[11]);
      float s03 = (sa0[12] + sa0[13]) + (sa0[14] + sa0[15]);
      float s10 = (sa1[0] + sa1[1]) + (sa1[2] + sa1[3]);
      float s11 = (sa1[4] + sa1[5]) + (sa1[6] + sa1[7]);
      float s12 = (sa1[8] + sa1[9]) + (sa1[10] + sa1[11]);
      float s13 = (sa1[12] + sa1[13]) + (sa1[14] + sa1[15]);
      l += ((s00 + s01) + (s02 + s03)) + ((s10 + s11) + (s12 + s13));

      // ---- pack P to bf16 + permlane32_swap -> B-fragments in registers ----
      unsigned w0[8], w1[8];
#pragma unroll
      for (int qd = 0; qd < 4; ++qd) {
        w0[qd * 2]     = cvt_pk_bf16(sa0[4 * qd],     sa0[4 * qd + 1]);
        w0[qd * 2 + 1] = cvt_pk_bf16(sa0[4 * qd + 2], sa0[4 * qd + 3]);
        w1[qd * 2]     = cvt_pk_bf16(sa1[4 * qd],     sa1[4 * qd + 1]);
        w1[qd * 2 + 1] = cvt_pk_bf16(sa1[4 * qd + 2], sa1[4 * qd + 3]);
      }
      bf16x8 pa[4];
#pragma unroll
      for (int c = 0; c < 4; ++c) {
        const unsigned* wt = (c < 2) ? w0 : w1;
        unsigned a0 = wt[(2 * (c & 1)) * 2],     b0 = wt[(2 * (c & 1) + 1) * 2];
        unsigned a1 = wt[(2 * (c & 1)) * 2 + 1], b1 = wt[(2 * (c & 1) + 1) * 2 + 1];
        pl32_swap(a0, b0);
        pl32_swap(a1, b1);
        uint4 u; u.x = a0; u.y = a1; u.z = b0; u.w = b1;
        pa[c] = __builtin_bit_cast(bf16x8, u);
      }

      // ---- O^T += V^T · P^T ----
#pragma unroll
      for (int c = 0; c < 4; ++c) {
        bf16x8 vf0 = *(const bf16x8*)(vbase + col * 128        + (((2 * c + h) ^ swz) << 4));
        bf16x8 vf1 = *(const bf16x8*)(vbase + (32 + col) * 128 + (((2 * c + h) ^ swz) << 4));
        acc0 = __builtin_amdgcn_mfma_f32_32x32x16_bf16(vf0, pa[c], acc0, 0, 0, 0);
        acc1 = __builtin_amdgcn_mfma_f32_32x32x16_bf16(vf1, pa[c], acc1, 0, 0, 0);
      }
    }
  }

  // ---- epilogue: un-normalized O^T (bf16) + (m, l) ----
  float lf = l + __shfl_xor(l, 32, 64);
  const int qrow = q0 + col;
  __bf16* ob = opart + ((size_t)(b * 8 + seg) * 4096 + qrow) * 64;
#pragma unroll
  for (int rq = 0; rq < 4; ++rq) {
    const int d0 = 8 * rq + 4 * h;
    bf16x4 o0 = {(__bf16)acc0[4 * rq], (__bf16)acc0[4 * rq + 1],
                 (__bf16)acc0[4 * rq + 2], (__bf16)acc0[4 * rq + 3]};
    bf16x4 o1 = {(__bf16)acc1[4 * rq], (__bf16)acc1[4 * rq + 1],
                 (__bf16)acc1[4 * rq + 2], (__bf16)acc1[4 * rq + 3]};
    *(bf16x4*)(ob + d0)      = o0;
    *(bf16x4*)(ob + 32 + d0) = o1;
  }
  if (h == 0) {
    float2 mlv; mlv.x = m; mlv.y = lf;   // m in log2 domain
    *(float2*)(mlpart + ((size_t)(b * 8 + seg) * 4096 + qrow) * 2) = mlv;
  }
}

// ---------------- 4) split-K combine (8 segs, exp2 domain) + proj + residual ----------------
__global__ __launch_bounds__(256) void proj_k(const __bf16* __restrict__ opart,
                                              const float* __restrict__ mlpart,
                                              const float* __restrict__ x,
                                              const float* __restrict__ w_proj,
                                              const float* __restrict__ b_proj,
                                              float* __restrict__ out) {
  __shared__ float wseg[8][32];
  __shared__ float a_lds[32 * 68];
  __shared__ float o_lds[64 * 33];
  const int t  = threadIdx.x;
  const int b  = blockIdx.x >> 7;
  const int s0 = (blockIdx.x & 127) * 32;

  if (t < 32) {
    const int rowg = s0 + t;
    float ms[8], ls[8], es[8];
    float M = -1e30f;
#pragma unroll
    for (int s = 0; s < 8; ++s) {
      float2 ml = *(const float2*)(mlpart + ((size_t)(b * 8 + s) * 4096 + rowg) * 2);
      ms[s] = ml.x; ls[s] = ml.y;
      M = fmaxf(M, ms[s]);
    }
    float L = 0.f;
#pragma unroll
    for (int s = 0; s < 8; ++s) { es[s] = exp2f(ms[s] - M); L += es[s] * ls[s]; }
    float invL = 1.f / L;
#pragma unroll
    for (int s = 0; s < 8; ++s) wseg[s][t] = es[s] * invL;
  }
  __syncthreads();

  for (int i = t; i < 512; i += 256) {
    const int px = i >> 4, c4 = i & 15;
    const __bf16* obase = opart + ((size_t)(b * 8) * 4096 + s0 + px) * 64 + c4 * 4;
    float4 a = {0.f, 0.f, 0.f, 0.f};
#pragma unroll
    for (int s = 0; s < 8; ++s) {
      bf16x4 v = *(const bf16x4*)(obase + (size_t)s * 4096 * 64);
      float wv = wseg[s][px];
      a.x += wv * (float)v[0]; a.y += wv * (float)v[1];
      a.z += wv * (float)v[2]; a.w += wv * (float)v[3];
    }
    *(float4*)(&a_lds[px * 68 + c4 * 4]) = a;
  }

  const int o = t & 63, wg = t >> 6;
  float4 wr[16];
  const float4* wrow = (const float4*)(w_proj + o * 64);
#pragma unroll
  for (int i = 0; i < 16; ++i) wr[i] = wrow[i];
  const float bias = b_proj[o];
  __syncthreads();

  for (int pp = 0; pp < 8; ++pp) {
    const int px = wg * 8 + pp;
    const float4* ar = (const float4*)&a_lds[px * 68];
    float a0 = bias, a1 = 0.f, a2 = 0.f, a3 = 0.f;
#pragma unroll
    for (int i = 0; i < 16; i += 4) {
      float4 x0 = ar[i], x1 = ar[i + 1], x2 = ar[i + 2], x3 = ar[i + 3];
      a0 += wr[i    ].x * x0.x + wr[i    ].y * x0.y + wr[i    ].z * x0.z + wr[i    ].w * x0.w;
      a1 += wr[i + 1].x * x1.x + wr[i + 1].y * x1.y + wr[i + 1].z * x1.z + wr[i + 1].w * x1.w;
      a2 += wr[i + 2].x * x2.x + wr[i + 2].y * x2.y + wr[i + 2].z * x2.z + wr[i + 2].w * x2.w;
      a3 += wr[i + 3].x * x3.x + wr[i + 3].y * x3.y + wr[i + 3].z * x3.z + wr[i + 3].w * x3.w;
    }
    o_lds[o * 33 + px] = (a0 + a1) + (a2 + a3);
  }
  __syncthreads();
  for (int idx = t; idx < 2048; idx += 256) {
    const int c = idx >> 5, px = idx & 31;
    const size_t gi = ((size_t)(b * 64 + c)) * 4096 + s0 + px;
    out[gi] = o_lds[c * 33 + px] + x[gi];
  }
}

// ---------------- launch ----------------
extern "C" void kernel_launch(void* const* d_in, const int* in_sizes, int n_in,
                              void* d_out, int out_size, void* d_ws, size_t ws_size,
                              hipStream_t stream) {
  const float* x      = (const float*)d_in[0];
  const float* gamma  = (const float*)d_in[1];
  const float* beta   = (const float*)d_in[2];
  const float* w_qkv  = (const float*)d_in[3];
  const float* b_qkv  = (const float*)d_in[4];
  const float* w_proj = (const float*)d_in[5];
  const float* b_proj = (const float*)d_in[6];
  float* out = (float*)d_out;

  char* ws = (char*)d_ws;
  float*  partial = (float*)ws;                          // 512 f32  @ 0
  __bf16* whi     = (__bf16*)(ws + 4096);                // 24KB
  __bf16* wlo     = whi + 12288;                         // 24KB
  __bf16* qb  = (__bf16*)(ws + 65536);                   // 2MB
  __bf16* kb  = qb  + (size_t)4 * 4096 * 64;             // 2MB
  __bf16* vtb = kb  + (size_t)4 * 4096 * 64;             // 2MB
  __bf16* opart = vtb + (size_t)4 * 4096 * 64;           // 16MB (bf16)
  float*  mlpart = (float*)(opart + (size_t)4 * 8 * 4096 * 64);  // 1MB

  gn_partial_k<<<256, 256, 0, stream>>>(x, w_qkv, partial, whi, wlo);
  qkv_k<<<256, 256, 0, stream>>>(x, partial, gamma, beta, whi, wlo, b_qkv, qb, kb, vtb);
  attn_k<<<512, 512, 0, stream>>>(qb, kb, vtb, opart, mlpart);
  proj_k<<<512, 256, 0, stream>>>(opart, mlpart, x, w_proj, b_proj, out);
}

// Round 20
// 65.358 us; speedup vs baseline: 1.0345x; 1.0163x over previous
//
#include <hip/hip_runtime.h>

typedef __bf16 bf16x8 __attribute__((ext_vector_type(8)));
typedef __bf16 bf16x4 __attribute__((ext_vector_type(4)));
typedef float  f32x4  __attribute__((ext_vector_type(4)));
typedef float  f32x16 __attribute__((ext_vector_type(16)));

#define GLD_LDS16(gsrc, ldst) \
  __builtin_amdgcn_global_load_lds((const __attribute__((address_space(1))) void*)(gsrc), \
                                   (__attribute__((address_space(3))) void*)(ldst), 16, 0, 0)

__device__ inline unsigned cvt_pk_bf16(float lo, float hi) {
  unsigned r;
  asm("v_cvt_pk_bf16_f32 %0, %1, %2" : "=v"(r) : "v"(lo), "v"(hi));
  return r;
}
__device__ inline void pl32_swap(unsigned& a, unsigned& b) {
  // NOTE: a and b MUST be distinct values; two copies of one value can be
  // register-coalesced -> in-place half-swap -> silent corruption (round-16 bug).
  asm volatile("v_permlane32_swap_b32 %0, %1" : "+v"(a), "+v"(b));
}
// 3-input max: clang fuses fmaxf(fmaxf(a,b),c) into v_max3_f32 on gfx9+ (T17)
__device__ inline float max3f(float a, float b, float c) {
  return fmaxf(fmaxf(a, b), c);
}
__device__ inline f32x16 zero16() {
  f32x16 z;
#pragma unroll
  for (int i = 0; i < 16; ++i) z[i] = 0.f;
  return z;
}

// ---------------- 1) GroupNorm partial sums (+ one-time w_qkv hi/lo split) ----------------
__global__ __launch_bounds__(256) void gn_partial_k(const float* __restrict__ x,
                                                    const float* __restrict__ w_qkv,
                                                    float* __restrict__ partial,
                                                    __bf16* __restrict__ whi,
                                                    __bf16* __restrict__ wlo) {
  __shared__ float red[2][4];
  const int t = threadIdx.x;
  if (blockIdx.x < 48) {   // split w_qkv (192x64) into bf16 hi/lo once
    const int idx = blockIdx.x * 256 + t;
    float wv = w_qkv[idx];
    __bf16 hh = (__bf16)wv;
    whi[idx] = hh;
    wlo[idx] = (__bf16)(wv - (float)hh);
  }
  const float4* base = (const float4*)(x + (size_t)blockIdx.x * 4096);
  float s = 0.f, sq = 0.f;
#pragma unroll
  for (int kk = 0; kk < 4; ++kk) {
    float4 v = base[t + kk * 256];
    s  += (v.x + v.y) + (v.z + v.w);
    sq += (v.x * v.x + v.y * v.y) + (v.z * v.z + v.w * v.w);
  }
#pragma unroll
  for (int o = 32; o >= 1; o >>= 1) {
    s  += __shfl_down(s, o, 64);
    sq += __shfl_down(sq, o, 64);
  }
  if ((t & 63) == 0) { red[0][t >> 6] = s; red[1][t >> 6] = sq; }
  __syncthreads();
  if (t == 0) {
    float S  = (red[0][0] + red[0][1]) + (red[0][2] + red[0][3]);
    float SQ = (red[1][0] + red[1][1]) + (red[1][2] + red[1][3]);
    partial[blockIdx.x * 2]     = S;
    partial[blockIdx.x * 2 + 1] = SQ;
  }
}

// ---------------- 2) QKV split-precision MFMA GEMM, gn_final fused in-block ----------------
__global__ __launch_bounds__(256) void qkv_k(const float* __restrict__ x,
                                             const float* __restrict__ partial,
                                             const float* __restrict__ gamma,
                                             const float* __restrict__ beta,
                                             const __bf16* __restrict__ whi,
                                             const __bf16* __restrict__ wlo,
                                             const float* __restrict__ b_qkv,
                                             __bf16* __restrict__ qo,
                                             __bf16* __restrict__ ko,
                                             __bf16* __restrict__ vto) {
  __shared__ float mu_s[8], rs_s[8], sc_l[128];
  const int tid  = threadIdx.x;
  const int lane = tid & 63, w = tid >> 6;
  const int px16 = lane & 15, grp = lane >> 4;
  const int b    = blockIdx.x >> 6;
  const int s0   = (blockIdx.x & 63) * 64;
  const int pxg  = s0 + w * 16 + px16;

  if (tid < 8) {
    float S = 0.f, SQ = 0.f;
#pragma unroll
    for (int i = 0; i < 8; ++i) {
      S  += partial[((b * 8 + tid) * 8 + i) * 2];
      SQ += partial[((b * 8 + tid) * 8 + i) * 2 + 1];
    }
    float mean = S * (1.f / 32768.f);
    float var  = SQ * (1.f / 32768.f) - mean * mean;
    mu_s[tid] = mean;
    rs_s[tid] = rsqrtf(fmaxf(var, 0.f) + 1e-5f);
  }
  __syncthreads();
  if (tid < 64) {
    const int g = tid >> 3;
    float scale = rs_s[g] * gamma[tid];
    sc_l[tid * 2]     = scale;
    sc_l[tid * 2 + 1] = beta[tid] - mu_s[g] * scale;
  }
  __syncthreads();

  bf16x8 bh[2], bl[2];
#pragma unroll
  for (int kk = 0; kk < 2; ++kk) {
    bf16x8 hv, lv;
#pragma unroll
    for (int i = 0; i < 8; ++i) {
      const int c = kk * 32 + grp * 8 + i;
      float xv = x[((size_t)(b * 64 + c) * 4096) + pxg];
      float xn = fmaf(xv, sc_l[c * 2], sc_l[c * 2 + 1]);
      __bf16 hh = (__bf16)xn;
      hv[i] = hh;
      lv[i] = (__bf16)(xn - (float)hh);
    }
    bh[kk] = hv;
    bl[kk] = lv;
  }

  f32x4 acc[12];
#pragma unroll
  for (int ot = 0; ot < 12; ++ot) {
    const int o = ot * 16 + px16;
    f32x4 a = {0.f, 0.f, 0.f, 0.f};
#pragma unroll
    for (int kk = 0; kk < 2; ++kk) {
      const size_t wo = (size_t)o * 64 + kk * 32 + grp * 8;
      bf16x8 ah = *(const bf16x8*)(whi + wo);
      bf16x8 al = *(const bf16x8*)(wlo + wo);
      a = __builtin_amdgcn_mfma_f32_16x16x32_bf16(ah, bh[kk], a, 0, 0, 0);
      a = __builtin_amdgcn_mfma_f32_16x16x32_bf16(ah, bl[kk], a, 0, 0, 0);
      a = __builtin_amdgcn_mfma_f32_16x16x32_bf16(al, bh[kk], a, 0, 0, 0);
    }
    acc[ot] = a;
  }

#pragma unroll
  for (int ot = 0; ot < 4; ++ot) {   // Q, pre-scaled 0.125*log2(e)
    const int ob = ot * 16 + grp * 4;
    float4 bias = *(const float4*)(b_qkv + ob);
    f32x4 a = acc[ot];
    bf16x4 qv = {(__bf16)((a[0] + bias.x) * 0.18033688f),
                 (__bf16)((a[1] + bias.y) * 0.18033688f),
                 (__bf16)((a[2] + bias.z) * 0.18033688f),
                 (__bf16)((a[3] + bias.w) * 0.18033688f)};
    *(bf16x4*)(qo + ((size_t)b * 4096 + pxg) * 64 + ob) = qv;
  }
#pragma unroll
  for (int ot = 4; ot < 8; ++ot) {   // K
    const int ob = (ot - 4) * 16 + grp * 4;
    float4 bias = *(const float4*)(b_qkv + 64 + ob);
    f32x4 a = acc[ot];
    bf16x4 kv = {(__bf16)(a[0] + bias.x), (__bf16)(a[1] + bias.y),
                 (__bf16)(a[2] + bias.z), (__bf16)(a[3] + bias.w)};
    *(bf16x4*)(ko + ((size_t)b * 4096 + pxg) * 64 + ob) = kv;
  }
#pragma unroll
  for (int ot = 8; ot < 12; ++ot) {  // V^T
    const int ob = (ot - 8) * 16 + grp * 4;
    float4 bias = *(const float4*)(b_qkv + 128 + ob);
    f32x4 a = acc[ot];
#pragma unroll
    for (int r = 0; r < 4; ++r) {
      float bv = (r == 0) ? bias.x : (r == 1) ? bias.y : (r == 2) ? bias.z : bias.w;
      vto[((size_t)(b * 64 + ob + r)) * 4096 + pxg] = (__bf16)(a[r] + bv);
    }
  }
}

// ---------------- 3) flash attention: 4-buffer, 2 tiles/barrier; max3 softmax reduce ----------------
// Round-17 verified skeleton; only change: v_max3-fusable max tree (T17) on the critical path.
__global__ __launch_bounds__(512, 2) void attn_k(const __bf16* __restrict__ q,
                                                 const __bf16* __restrict__ k,
                                                 const __bf16* __restrict__ vt,
                                                 __bf16* __restrict__ opart,
                                                 float* __restrict__ mlpart) {
  __shared__ __bf16 k_lds[4][4096];   // 64 keys x 64 d each, swizzled slots (8KB)
  __shared__ __bf16 v_lds[4][4096];   // 64 d x 64 keys each, swizzled slots

  const int tid  = threadIdx.x;
  const int lane = tid & 63, w = tid >> 6;
  const int col  = lane & 31;
  const int h    = lane >> 5;
  const int swz  = col & 7;

  const int blk  = blockIdx.x;
  const int xcd  = blk & 7;
  const int b    = xcd >> 1;
  const int rest = blk >> 3;
  const int seg  = rest >> 3;
  const int qblk = (rest & 7) | ((xcd & 1) << 3);
  const int q0   = qblk * 256 + w * 32;
  const int j0b  = seg * 512;

  const __bf16* qp = q  + (size_t)b * 4096 * 64;
  const __bf16* kp = k  + (size_t)b * 4096 * 64;
  const __bf16* vp = vt + (size_t)b * 64 * 4096;

  bf16x8 qf[4];
#pragma unroll
  for (int kk = 0; kk < 4; ++kk)
    qf[kk] = *(const bf16x8*)(qp + (size_t)(q0 + col) * 64 + kk * 16 + h * 8);
  __builtin_amdgcn_sched_barrier(0);   // pin qf loads before staging (vmcnt ledger)

  f32x16 acc0 = zero16(), acc1 = zero16();
  float m = -1e30f, l = 0.f;

  const int soff = tid * 16;
  const int sj = soff >> 7;
  const int sc2 = ((soff >> 4) & 7) ^ (sj & 7);

  auto stage = [&](int buf, int j0) {
    GLD_LDS16(kp + (size_t)(j0 + sj) * 64 + sc2 * 8, (char*)(&k_lds[buf][0]) + soff);
    GLD_LDS16(vp + (size_t)sj * 4096 + j0 + sc2 * 8, (char*)(&v_lds[buf][0]) + soff);
  };

  stage(0, j0b);
  stage(1, j0b + 64);
  stage(2, j0b + 128);
  stage(3, j0b + 192);

#pragma unroll
  for (int kt = 0; kt < 4; ++kt) {
    // wait for this iteration's TWO tiles (2kt, 2kt+1)
    if (kt == 0) asm volatile("s_waitcnt vmcnt(4)" ::: "memory");
    else         asm volatile("s_waitcnt vmcnt(0)" ::: "memory");
    __builtin_amdgcn_s_barrier();      // loads landed + previous iter's buffers retired

    if (kt == 1) { stage(0, j0b + 256); stage(1, j0b + 320); }  // t4,t5 -> b0,b1
    if (kt == 2) { stage(2, j0b + 384); stage(3, j0b + 448); }  // t6,t7 -> b2,b3

#pragma unroll
    for (int sub = 0; sub < 2; ++sub) {
      const int buf = (2 * kt + sub) & 3;
      const char* kbase = (const char*)&k_lds[buf][0];
      const char* vbase = (const char*)&v_lds[buf][0];

      // ---- S^T = K · Q^T (exp2 domain) ----
      f32x16 sa0 = zero16(), sa1 = zero16();
#pragma unroll
      for (int kk = 0; kk < 4; ++kk) {
        bf16x8 kf0 = *(const bf16x8*)(kbase + col * 128        + (((2 * kk + h) ^ swz) << 4));
        bf16x8 kf1 = *(const bf16x8*)(kbase + (32 + col) * 128 + (((2 * kk + h) ^ swz) << 4));
        sa0 = __builtin_amdgcn_mfma_f32_32x32x16_bf16(kf0, qf[kk], sa0, 0, 0, 0);
        sa1 = __builtin_amdgcn_mfma_f32_32x32x16_bf16(kf1, qf[kk], sa1, 0, 0, 0);
      }

      // ---- online softmax, defer-rescale (T13, THR=8 in log2 units) ----
      // max via v_max3-fusable triples: 32 values -> 10 max3 + tree (~14 ops vs 31)
      float a0 = max3f(sa0[0],  sa0[1],  sa0[2]);
      float a1 = max3f(sa0[3],  sa0[4],  sa0[5]);
      float a2 = max3f(sa0[6],  sa0[7],  sa0[8]);
      float a3 = max3f(sa0[9],  sa0[10], sa0[11]);
      float a4 = max3f(sa0[12], sa0[13], sa0[14]);
      float a5 = max3f(sa1[0],  sa1[1],  sa1[2]);
      float a6 = max3f(sa1[3],  sa1[4],  sa1[5]);
      float a7 = max3f(sa1[6],  sa1[7],  sa1[8]);
      float a8 = max3f(sa1[9],  sa1[10], sa1[11]);
      float a9 = max3f(sa1[12], sa1[13], sa1[14]);
      float b0m = max3f(a0, a1, a2);
      float b1m = max3f(a3, a4, sa0[15]);
      float b2m = max3f(a5, a6, a7);
      float b3m = max3f(a8, a9, sa1[15]);
      float mx  = max3f(max3f(b0m, b1m, b2m), b3m, -1e30f);
      mx = fmaxf(mx, __shfl_xor(mx, 32, 64));
      if (!__all(mx <= m + 8.f)) {     // rescale only when the running max really grew
        float mn = fmaxf(m, mx);
        float sf = exp2f(m - mn);
        m = mn;
        l *= sf;
        acc0 *= sf;
        acc1 *= sf;
      }
#pragma unroll
      for (int r = 0; r < 16; ++r) sa0[r] = exp2f(sa0[r] - m);
#pragma unroll
      for (int r = 0; r < 16; ++r) sa1[r] = exp2f(sa1[r] - m);
      // pairwise tree-sum (5-level dep chain)
      float s00 = (sa0[0] + sa0[1]) + (sa0[2] + sa0[3]);
      float s01 = (sa0[4] + sa0[5]) + (sa0[6] + sa0[7]);
      float s02 = (sa0[8] + sa0[9]) + (sa0[10] + sa0[11]);
      float s03 = (sa0[12] + sa0[13]) + (sa0[14] + sa0[15]);
      float s10 = (sa1[0] + sa1[1]) + (sa1[2] + sa1[3]);
      float s11 = (sa1[4] + sa1[5]) + (sa1[6] + sa1[7]);
      float s12 = (sa1[8] + sa1[9]) + (sa1[10] + sa1[11]);
      float s13 = (sa1[12] + sa1[13]) + (sa1[14] + sa1[15]);
      l += ((s00 + s01) + (s02 + s03)) + ((s10 + s11) + (s12 + s13));

      // ---- pack P to bf16 + permlane32_swap -> B-fragments in registers ----
      unsigned w0[8], w1[8];
#pragma unroll
      for (int qd = 0; qd < 4; ++qd) {
        w0[qd * 2]     = cvt_pk_bf16(sa0[4 * qd],     sa0[4 * qd + 1]);
        w0[qd * 2 + 1] = cvt_pk_bf16(sa0[4 * qd + 2], sa0[4 * qd + 3]);
        w1[qd * 2]     = cvt_pk_bf16(sa1[4 * qd],     sa1[4 * qd + 1]);
        w1[qd * 2 + 1] = cvt_pk_bf16(sa1[4 * qd + 2], sa1[4 * qd + 3]);
      }
      bf16x8 pa[4];
#pragma unroll
      for (int c = 0; c < 4; ++c) {
        const unsigned* wt = (c < 2) ? w0 : w1;
        unsigned p0 = wt[(2 * (c & 1)) * 2],     p1 = wt[(2 * (c & 1) + 1) * 2];
        unsigned p2 = wt[(2 * (c & 1)) * 2 + 1], p3 = wt[(2 * (c & 1) + 1) * 2 + 1];
        pl32_swap(p0, p1);
        pl32_swap(p2, p3);
        uint4 u; u.x = p0; u.y = p2; u.z = p1; u.w = p3;
        pa[c] = __builtin_bit_cast(bf16x8, u);
      }

      // ---- O^T += V^T · P^T ----
#pragma unroll
      for (int c = 0; c < 4; ++c) {
        bf16x8 vf0 = *(const bf16x8*)(vbase + col * 128        + (((2 * c + h) ^ swz) << 4));
        bf16x8 vf1 = *(const bf16x8*)(vbase + (32 + col) * 128 + (((2 * c + h) ^ swz) << 4));
        acc0 = __builtin_amdgcn_mfma_f32_32x32x16_bf16(vf0, pa[c], acc0, 0, 0, 0);
        acc1 = __builtin_amdgcn_mfma_f32_32x32x16_bf16(vf1, pa[c], acc1, 0, 0, 0);
      }
    }
  }

  // ---- epilogue: un-normalized O^T (bf16) + (m, l) ----
  float lf = l + __shfl_xor(l, 32, 64);
  const int qrow = q0 + col;
  __bf16* ob = opart + ((size_t)(b * 8 + seg) * 4096 + qrow) * 64;
#pragma unroll
  for (int rq = 0; rq < 4; ++rq) {
    const int d0 = 8 * rq + 4 * h;
    bf16x4 o0 = {(__bf16)acc0[4 * rq], (__bf16)acc0[4 * rq + 1],
                 (__bf16)acc0[4 * rq + 2], (__bf16)acc0[4 * rq + 3]};
    bf16x4 o1 = {(__bf16)acc1[4 * rq], (__bf16)acc1[4 * rq + 1],
                 (__bf16)acc1[4 * rq + 2], (__bf16)acc1[4 * rq + 3]};
    *(bf16x4*)(ob + d0)      = o0;
    *(bf16x4*)(ob + 32 + d0) = o1;
  }
  if (h == 0) {
    float2 mlv; mlv.x = m; mlv.y = lf;   // m in log2 domain
    *(float2*)(mlpart + ((size_t)(b * 8 + seg) * 4096 + qrow) * 2) = mlv;
  }
}

// ---------------- 4) split-K combine (8 segs, exp2 domain) + proj + residual ----------------
__global__ __launch_bounds__(256) void proj_k(const __bf16* __restrict__ opart,
                                              const float* __restrict__ mlpart,
                                              const float* __restrict__ x,
                                              const float* __restrict__ w_proj,
                                              const float* __restrict__ b_proj,
                                              float* __restrict__ out) {
  __shared__ float wseg[8][32];
  __shared__ float a_lds[32 * 68];
  __shared__ float o_lds[64 * 33];
  const int t  = threadIdx.x;
  const int b  = blockIdx.x >> 7;
  const int s0 = (blockIdx.x & 127) * 32;

  if (t < 32) {
    const int rowg = s0 + t;
    float ms[8], ls[8], es[8];
    float M = -1e30f;
#pragma unroll
    for (int s = 0; s < 8; ++s) {
      float2 ml = *(const float2*)(mlpart + ((size_t)(b * 8 + s) * 4096 + rowg) * 2);
      ms[s] = ml.x; ls[s] = ml.y;
      M = fmaxf(M, ms[s]);
    }
    float L = 0.f;
#pragma unroll
    for (int s = 0; s < 8; ++s) { es[s] = exp2f(ms[s] - M); L += es[s] * ls[s]; }
    float invL = 1.f / L;
#pragma unroll
    for (int s = 0; s < 8; ++s) wseg[s][t] = es[s] * invL;
  }
  __syncthreads();

  for (int i = t; i < 512; i += 256) {
    const int px = i >> 4, c4 = i & 15;
    const __bf16* obase = opart + ((size_t)(b * 8) * 4096 + s0 + px) * 64 + c4 * 4;
    float4 a = {0.f, 0.f, 0.f, 0.f};
#pragma unroll
    for (int s = 0; s < 8; ++s) {
      bf16x4 v = *(const bf16x4*)(obase + (size_t)s * 4096 * 64);
      float wv = wseg[s][px];
      a.x += wv * (float)v[0]; a.y += wv * (float)v[1];
      a.z += wv * (float)v[2]; a.w += wv * (float)v[3];
    }
    *(float4*)(&a_lds[px * 68 + c4 * 4]) = a;
  }

  const int o = t & 63, wg = t >> 6;
  float4 wr[16];
  const float4* wrow = (const float4*)(w_proj + o * 64);
#pragma unroll
  for (int i = 0; i < 16; ++i) wr[i] = wrow[i];
  const float bias = b_proj[o];
  __syncthreads();

  for (int pp = 0; pp < 8; ++pp) {
    const int px = wg * 8 + pp;
    const float4* ar = (const float4*)&a_lds[px * 68];
    float a0 = bias, a1 = 0.f, a2 = 0.f, a3 = 0.f;
#pragma unroll
    for (int i = 0; i < 16; i += 4) {
      float4 x0 = ar[i], x1 = ar[i + 1], x2 = ar[i + 2], x3 = ar[i + 3];
      a0 += wr[i    ].x * x0.x + wr[i    ].y * x0.y + wr[i    ].z * x0.z + wr[i    ].w * x0.w;
      a1 += wr[i + 1].x * x1.x + wr[i + 1].y * x1.y + wr[i + 1].z * x1.z + wr[i + 1].w * x1.w;
      a2 += wr[i + 2].x * x2.x + wr[i + 2].y * x2.y + wr[i + 2].z * x2.z + wr[i + 2].w * x2.w;
      a3 += wr[i + 3].x * x3.x + wr[i + 3].y * x3.y + wr[i + 3].z * x3.z + wr[i + 3].w * x3.w;
    }
    o_lds[o * 33 + px] = (a0 + a1) + (a2 + a3);
  }
  __syncthreads();
  for (int idx = t; idx < 2048; idx += 256) {
    const int c = idx >> 5, px = idx & 31;
    const size_t gi = ((size_t)(b * 64 + c)) * 4096 + s0 + px;
    out[gi] = o_lds[c * 33 + px] + x[gi];
  }
}

// ---------------- launch ----------------
extern "C" void kernel_launch(void* const* d_in, const int* in_sizes, int n_in,
                              void* d_out, int out_size, void* d_ws, size_t ws_size,
                              hipStream_t stream) {
  const float* x      = (const float*)d_in[0];
  const float* gamma  = (const float*)d_in[1];
  const float* beta   = (const float*)d_in[2];
  const float* w_qkv  = (const float*)d_in[3];
  const float* b_qkv  = (const float*)d_in[4];
  const float* w_proj = (const float*)d_in[5];
  const float* b_proj = (const float*)d_in[6];
  float* out = (float*)d_out;

  char* ws = (char*)d_ws;
  float*  partial = (float*)ws;                          // 512 f32  @ 0
  __bf16* whi     = (__bf16*)(ws + 4096);                // 24KB
  __bf16* wlo     = whi + 12288;                         // 24KB
  __bf16* qb  = (__bf16*)(ws + 65536);                   // 2MB
  __bf16* kb  = qb  + (size_t)4 * 4096 * 64;             // 2MB
  __bf16* vtb = kb  + (size_t)4 * 4096 * 64;             // 2MB
  __bf16* opart = vtb + (size_t)4 * 4096 * 64;           // 16MB (bf16)
  float*  mlpart = (float*)(opart + (size_t)4 * 8 * 4096 * 64);  // 1MB

  gn_partial_k<<<256, 256, 0, stream>>>(x, w_qkv, partial, whi, wlo);
  qkv_k<<<256, 256, 0, stream>>>(x, partial, gamma, beta, whi, wlo, b_qkv, qb, kb, vtb);
  attn_k<<<512, 512, 0, stream>>>(qb, kb, vtb, opart, mlpart);
  proj_k<<<512, 256, 0, stream>>>(opart, mlpart, x, w_proj, b_proj, out);
}